// Round 1
// baseline (1558.760 us; speedup 1.0000x reference)
//
#include <hip/hip_runtime.h>
#include <hip/hip_bf16.h>
#include <math.h>

#define DIM 384
#define HEADS 6
#define NN 3136
#define BB 16
#define BH (BB*HEADS)

typedef __attribute__((ext_vector_type(8))) short short8;
typedef __attribute__((ext_vector_type(4))) short short4v;
typedef __attribute__((ext_vector_type(4))) float f32x4;

__device__ __forceinline__ float bf2f(unsigned short u) {
    union { unsigned int i; float f; } v; v.i = ((unsigned int)u) << 16; return v.f;
}
__device__ __forceinline__ unsigned short f2bf(float f) {
    union { float f; unsigned int i; } v; v.f = f;
    unsigned int r = v.i + 0x7fffu + ((v.i >> 16) & 1u);
    return (unsigned short)(r >> 16);
}

// ---------------- weight conversion / rearrange ----------------
__global__ void kw_convert(const float* __restrict__ qkv_w, const float* __restrict__ proj_w,
                           const float* __restrict__ conv_w,
                           unsigned short* __restrict__ Wq, unsigned short* __restrict__ Wp,
                           unsigned short* __restrict__ Wc) {
    int tid = blockIdx.x * 256 + threadIdx.x;
    int stride = gridDim.x * 256;
    for (int i = tid; i < 3*DIM*DIM; i += stride) Wq[i] = f2bf(qkv_w[i]);
    for (int i = tid; i < DIM*DIM; i += stride) Wp[i] = f2bf(proj_w[i]);
    for (int i = tid; i < DIM*DIM*9; i += stride) {
        // dst layout: [o][tap][i]   src: (o, i, ky, kx) -> (o*384+i)*9 + tap
        int ii = i % DIM; int rest = i / DIM; int tap = rest % 9; int o = rest / 9;
        Wc[i] = f2bf(conv_w[(size_t)(o*DIM + ii)*9 + tap]);
    }
}

// ---------------- positional encoding table P[n][c] ----------------
__global__ void k_pos(const float* __restrict__ pos_w, const float* __restrict__ pos_b,
                      float* __restrict__ P) {
    int n = blockIdx.x; int h = n / 56, w = n % 56;
    __shared__ float feat[64];
    int t = threadIdx.x;
    if (t < 64) {
        int axis = t >> 5;      // 0 = y (h), 1 = x (w)
        int k = t & 31; int i = k >> 1;
        float e = (float)((axis ? w : h) + 1) / 56.000001f * 6.28318530717958647692f;
        float arg = e / powf(10000.0f, (float)i / 16.0f);
        feat[t] = (k & 1) ? cosf(arg) : sinf(arg);
    }
    __syncthreads();
    for (int c = t; c < DIM; c += blockDim.x) {
        float s = pos_b[c];
        #pragma unroll 8
        for (int k = 0; k < 64; k++) s += feat[k] * pos_w[c*64 + k];
        P[(size_t)n*DIM + c] = s;
    }
}

// ---------------- transpose + pos add: XT[b][n][c] = x[b][c][n] + P[n][c] ----------------
__global__ __launch_bounds__(256) void k_tadd(const float* __restrict__ x, const float* __restrict__ P,
                                              float* __restrict__ XT) {
    int mt = blockIdx.x, ct = blockIdx.y, b = blockIdx.z;
    __shared__ float tile[64][65];
    int t = threadIdx.x;
    int n0 = mt*64, c0 = ct*64;
    for (int q = t; q < 1024; q += 256) {
        int cc = q >> 4, nn4 = (q & 15) * 4;
        float4 v = *reinterpret_cast<const float4*>(x + ((size_t)(b*DIM + c0 + cc))*NN + n0 + nn4);
        tile[cc][nn4+0] = v.x; tile[cc][nn4+1] = v.y; tile[cc][nn4+2] = v.z; tile[cc][nn4+3] = v.w;
    }
    __syncthreads();
    for (int q = t; q < 1024; q += 256) {
        int nn = q >> 4, cc4 = (q & 15) * 4;
        float4 p = *reinterpret_cast<const float4*>(P + (size_t)(n0+nn)*DIM + c0 + cc4);
        float4 o;
        o.x = tile[cc4+0][nn] + p.x; o.y = tile[cc4+1][nn] + p.y;
        o.z = tile[cc4+2][nn] + p.z; o.w = tile[cc4+3][nn] + p.w;
        *reinterpret_cast<float4*>(XT + ((size_t)(b*NN + n0 + nn))*DIM + c0 + cc4) = o;
    }
}

// ---------------- layernorm: XN = LN(XT) in bf16 ----------------
__global__ __launch_bounds__(128) void k_ln(const float* __restrict__ XT, const float* __restrict__ g,
                                            const float* __restrict__ be, unsigned short* __restrict__ XN) {
    int row = blockIdx.x;
    int t = threadIdx.x;
    const float* src = XT + (size_t)row*DIM;
    float v0 = src[t], v1 = src[t+128], v2 = src[t+256];
    __shared__ float red[2], red2[2];
    float s = v0 + v1 + v2;
    for (int off = 32; off; off >>= 1) s += __shfl_down(s, off, 64);
    if ((t & 63) == 0) red[t >> 6] = s;
    __syncthreads();
    float mean = (red[0] + red[1]) * (1.0f/384.0f);
    float d0 = v0-mean, d1 = v1-mean, d2 = v2-mean;
    float sq = d0*d0 + d1*d1 + d2*d2;
    for (int off = 32; off; off >>= 1) sq += __shfl_down(sq, off, 64);
    if ((t & 63) == 0) red2[t >> 6] = sq;
    __syncthreads();
    float rs = rsqrtf((red2[0] + red2[1]) * (1.0f/384.0f) + 1e-6f);
    unsigned short* dst = XN + (size_t)row*DIM;
    dst[t]     = f2bf(d0*rs*g[t]     + be[t]);
    dst[t+128] = f2bf(d1*rs*g[t+128] + be[t+128]);
    dst[t+256] = f2bf(d2*rs*g[t+256] + be[t+256]);
}

// ---------------- unified MFMA GEMM: MODE 0 = qkv, 1 = proj, 2 = conv3x3 ----------------
template<int MODE>
__global__ __launch_bounds__(256) void k_gemm(
    const unsigned short* __restrict__ A, const unsigned short* __restrict__ Wt, int K,
    const float* __restrict__ bias,
    unsigned short* __restrict__ Qb, unsigned short* __restrict__ Kb, unsigned short* __restrict__ Vt,
    const float* __restrict__ XTp, const float* __restrict__ gxca, unsigned short* __restrict__ X2out,
    const float* __restrict__ bn_g, const float* __restrict__ bn_b,
    const float* __restrict__ bn_mean, const float* __restrict__ bn_var,
    float* __restrict__ Yout)
{
    int ct = blockIdx.x, mt = blockIdx.y;
    int m0 = mt*128, o0 = ct*128;
    __shared__ unsigned short As[128][40];
    __shared__ unsigned short Bs[128][40];
    int t = threadIdx.x;
    int wave = t >> 6, lane = t & 63;
    int wr = wave >> 1, wc = wave & 1;
    int lr = lane & 15, lg = lane >> 4;
    f32x4 acc[4][4];
    for (int i=0;i<4;i++) for (int j=0;j<4;j++) acc[i][j] = (f32x4){0.f,0.f,0.f,0.f};
    int ksteps = K >> 5;
    for (int ks = 0; ks < ksteps; ks++) {
        int k0 = ks << 5;
        for (int q = t; q < 512; q += 256) {
            int r = q >> 2, part = (q & 3) << 3;
            short8 v = {0,0,0,0,0,0,0,0};
            if (MODE == 2) {
                int m = m0 + r;
                int b = m / NN, n = m % NN;
                int tap = k0 / DIM, i0k = k0 - tap*DIM;
                int hh = n/56 + tap/3 - 1, ww2 = n%56 + tap%3 - 1;
                if (hh >= 0 && hh < 56 && ww2 >= 0 && ww2 < 56)
                    v = *reinterpret_cast<const short8*>(A + ((size_t)(b*NN + hh*56 + ww2))*DIM + i0k + part);
            } else {
                v = *reinterpret_cast<const short8*>(A + (size_t)(m0 + r)*K + k0 + part);
            }
            *reinterpret_cast<short8*>(&As[r][part]) = v;
        }
        for (int q = t; q < 512; q += 256) {
            int r = q >> 2, part = (q & 3) << 3;
            short8 v = *reinterpret_cast<const short8*>(Wt + (size_t)(o0 + r)*K + k0 + part);
            *reinterpret_cast<short8*>(&Bs[r][part]) = v;
        }
        __syncthreads();
        short8 af[4], bfv[4];
        for (int i=0;i<4;i++) af[i]  = *reinterpret_cast<short8*>(&As[wr*64 + i*16 + lr][lg*8]);
        for (int j=0;j<4;j++) bfv[j] = *reinterpret_cast<short8*>(&Bs[wc*64 + j*16 + lr][lg*8]);
        for (int i=0;i<4;i++)
            for (int j=0;j<4;j++)
                acc[i][j] = __builtin_amdgcn_mfma_f32_16x16x32_bf16(af[i], bfv[j], acc[i][j], 0, 0, 0);
        __syncthreads();
    }
    // epilogue
    for (int j=0;j<4;j++) {
        int o = o0 + wc*64 + j*16 + lr;
        float bv = 0.f, mean = 0.f, rs = 0.f, gg = 0.f, bb2 = 0.f;
        if (MODE == 2) { mean = bn_mean[o]; rs = rsqrtf(bn_var[o] + 1e-5f); gg = bn_g[o]; bb2 = bn_b[o]; }
        else bv = bias[o];
        for (int i=0;i<4;i++) {
            for (int r=0;r<4;r++) {
                int m = m0 + wr*64 + i*16 + lg*4 + r;
                float val = acc[i][j][r] + bv;
                if (MODE == 0) {
                    int b = m / NN, n = m % NN;
                    int comp = o / DIM, rem = o % DIM;
                    int hh = rem >> 6, dd = rem & 63;
                    int bh = b*HEADS + hh;
                    if (comp == 0)      Qb[((size_t)bh*64 + dd)*NN + n] = f2bf(val);
                    else if (comp == 1) Kb[((size_t)bh*64 + dd)*NN + n] = f2bf(val);
                    else                Vt[((size_t)bh*NN + n)*64 + dd] = f2bf(val);
                } else if (MODE == 1) {
                    float xt = XTp[(size_t)m*DIM + o];
                    X2out[(size_t)m*DIM + o] = f2bf(xt + gxca[o]*val);
                } else {
                    int b = m / NN, n = m % NN;
                    float xi = (val - mean)*rs*gg + bb2;
                    float si = xi / (1.0f + __expf(-xi));
                    float x2v = bf2f(A[(size_t)m*DIM + o]);
                    Yout[((size_t)(b*DIM) + o)*NN + n] = x2v + si;
                }
            }
        }
    }
}

// ---------------- XCA attention: norms + G=q k^T + softmax -> ATT bf16 ----------------
__global__ __launch_bounds__(256) void k_attn(const unsigned short* __restrict__ Qb,
                                              const unsigned short* __restrict__ Kb,
                                              const float* __restrict__ temperature,
                                              const float* __restrict__ rpb,
                                              unsigned short* __restrict__ ATT) {
    int bh = blockIdx.x; int h = bh % HEADS;
    int t = threadIdx.x, wave = t >> 6, lane = t & 63;
    int lr = lane & 15, lg = lane >> 4;
    __shared__ float qn[64], kn[64];
    {   // squared norms: 128 rows, 2 threads/row
        int row = t >> 1, p = t & 1;
        const unsigned short* src = (row < 64) ? Qb + ((size_t)bh*64 + row)*NN
                                               : Kb + ((size_t)bh*64 + (row-64))*NN;
        float s = 0.f;
        for (int cb = p; cb < NN/8; cb += 2) {
            short8 v = *reinterpret_cast<const short8*>(src + cb*8);
            for (int jj=0;jj<8;jj++) { float f = bf2f((unsigned short)v[jj]); s += f*f; }
        }
        s += __shfl_xor(s, 1, 64);
        if (p == 0) { if (row < 64) qn[row] = s; else kn[row-64] = s; }
    }
    __syncthreads();
    f32x4 acc[4];
    for (int j=0;j<4;j++) acc[j] = (f32x4){0.f,0.f,0.f,0.f};
    const unsigned short* qrow = Qb + ((size_t)bh*64 + wave*16 + lr)*NN;
    for (int ks = 0; ks < NN/32; ks++) {
        short8 a = *reinterpret_cast<const short8*>(qrow + ks*32 + lg*8);
        for (int j=0;j<4;j++) {
            short8 bfr = *reinterpret_cast<const short8*>(Kb + ((size_t)bh*64 + j*16 + lr)*NN + ks*32 + lg*8);
            acc[j] = __builtin_amdgcn_mfma_f32_16x16x32_bf16(a, bfr, acc[j], 0, 0, 0);
        }
    }
    float temp = temperature[h];
    float bias = rpb[HEADS + h];   // rpb_table[1][h]
    for (int r=0;r<4;r++) {
        int dq = wave*16 + lg*4 + r;
        float qnorm = fmaxf(sqrtf(qn[dq]), 1e-12f);
        float lv[4]; float mx = -1e30f;
        for (int j=0;j<4;j++) {
            float knorm = fmaxf(sqrtf(kn[j*16 + lr]), 1e-12f);
            lv[j] = acc[j][r] / (qnorm*knorm) * temp + bias;
            mx = fmaxf(mx, lv[j]);
        }
        for (int off=1; off<16; off<<=1) mx = fmaxf(mx, __shfl_xor(mx, off, 64));
        float se = 0.f;
        for (int j=0;j<4;j++) { lv[j] = __expf(lv[j]-mx); se += lv[j]; }
        for (int off=1; off<16; off<<=1) se += __shfl_xor(se, off, 64);
        float inv = 1.0f/se;
        for (int j=0;j<4;j++)
            ATT[((size_t)bh*64 + dq)*64 + j*16 + lr] = f2bf(lv[j]*inv);
    }
}

// ---------------- PV: XCA[b][n][h*64+dd] = sum_e ATT[dd][e] * V[e][n] ----------------
__global__ __launch_bounds__(256) void k_pv(const unsigned short* __restrict__ ATT,
                                            const unsigned short* __restrict__ Vt,
                                            unsigned short* __restrict__ XCA) {
    int nt = blockIdx.x, bh = blockIdx.y;
    int b = bh / HEADS, h = bh % HEADS;
    int t = threadIdx.x, wave = t >> 6, lane = t & 63;
    int lr = lane & 15, lg = lane >> 4;
    int n0 = nt*64 + wave*16;
    f32x4 acc[4];
    for (int i=0;i<4;i++) acc[i] = (f32x4){0.f,0.f,0.f,0.f};
    for (int ks=0; ks<2; ks++) {
        short8 bfr = *reinterpret_cast<const short8*>(Vt + ((size_t)bh*NN + n0 + lr)*64 + ks*32 + lg*8);
        for (int i=0;i<4;i++) {
            short8 a = *reinterpret_cast<const short8*>(ATT + ((size_t)bh*64 + i*16 + lr)*64 + ks*32 + lg*8);
            acc[i] = __builtin_amdgcn_mfma_f32_16x16x32_bf16(a, bfr, acc[i], 0, 0, 0);
        }
    }
    int n = n0 + lr;
    for (int i=0;i<4;i++) {
        unsigned short pack[4];
        for (int r=0;r<4;r++) pack[r] = f2bf(acc[i][r]);
        int dd = i*16 + lg*4;
        *reinterpret_cast<short4v*>(&XCA[((size_t)(b*NN + n))*DIM + h*64 + dd]) =
            *reinterpret_cast<short4v*>(pack);
    }
}

// ---------------- final: out = x + gamma-shuffled residual ----------------
__global__ __launch_bounds__(256) void k_final(const float* __restrict__ x, const float* __restrict__ Y,
                                               const float* __restrict__ gamma, float* __restrict__ out) {
    int i = blockIdx.x, b = blockIdx.y, kc = blockIdx.z;
    __shared__ float tile[56*193];
    int t = threadIdx.x;
    int k0 = kc*192;
    // Y is (B,C,N); needed value for (k,i,j) is Y_flat[b][i*21504 + j*384 + k] (contiguous!)
    const float* ybase = Y + (size_t)b*DIM*NN + (size_t)i*21504 + k0;
    for (int q = t; q < 56*48; q += 256) {
        int j = q / 48, c4 = (q % 48) * 4;
        float4 v = *reinterpret_cast<const float4*>(ybase + (size_t)j*384 + c4);
        float* dst = &tile[j*193 + c4];
        dst[0]=v.x; dst[1]=v.y; dst[2]=v.z; dst[3]=v.w;
    }
    __syncthreads();
    for (int q = t; q < 192*56; q += 256) {
        int kl = q / 56, j = q % 56;
        int k = k0 + kl;
        size_t gi = ((size_t)(b*DIM + k))*NN + (size_t)i*56 + j;
        out[gi] = x[gi] + gamma[k] * tile[j*193 + kl];
    }
}

extern "C" void kernel_launch(void* const* d_in, const int* in_sizes, int n_in,
                              void* d_out, int out_size, void* d_ws, size_t ws_size,
                              hipStream_t stream) {
    const float* x       = (const float*)d_in[0];
    const float* pos_w   = (const float*)d_in[1];
    const float* pos_b   = (const float*)d_in[2];
    const float* ln_g    = (const float*)d_in[3];
    const float* ln_b    = (const float*)d_in[4];
    const float* gxca    = (const float*)d_in[5];
    const float* temp    = (const float*)d_in[6];
    const float* qkv_w   = (const float*)d_in[7];
    const float* qkv_b   = (const float*)d_in[8];
    const float* proj_w  = (const float*)d_in[9];
    const float* proj_b  = (const float*)d_in[10];
    const float* rpb     = (const float*)d_in[11];
    const float* conv_w  = (const float*)d_in[12];
    const float* bn_g    = (const float*)d_in[13];
    const float* bn_b    = (const float*)d_in[14];
    const float* bn_mean = (const float*)d_in[15];
    const float* bn_var  = (const float*)d_in[16];
    const float* gamma   = (const float*)d_in[17];
    float* out = (float*)d_out;
    char* ws = (char*)d_ws;

    const size_t oP   = 0;                        // P: 4,816,896 B
    const size_t oXT  = oP   + 4816896;           // XT fp32: 77,070,336 B   (reused as Y)
    const size_t oXN  = oXT  + 77070336;          // XN bf16: 38,535,168 B   (reused as XCA)
    const size_t oQ   = oXN  + 38535168;          // Qb bf16                  (reused as X2)
    const size_t oK   = oQ   + 38535168;          // Kb bf16
    const size_t oV   = oK   + 38535168;          // Vt bf16
    const size_t oATT = oV   + 38535168;          // ATT bf16: 786,432 B
    const size_t oWq  = oATT + 786432;            // 884,736 B
    const size_t oWp  = oWq  + 884736;            // 294,912 B
    const size_t oWc  = oWp  + 294912;            // 2,654,208 B

    float* P            = (float*)(ws + oP);
    float* XT           = (float*)(ws + oXT);
    float* Y            = (float*)(ws + oXT);     // alias (XT dead after proj epilogue)
    unsigned short* XN  = (unsigned short*)(ws + oXN);
    unsigned short* XCA = (unsigned short*)(ws + oXN);  // alias (XN dead after qkv GEMM)
    unsigned short* Qb  = (unsigned short*)(ws + oQ);
    unsigned short* X2  = (unsigned short*)(ws + oQ);   // alias (Qb dead after k_attn)
    unsigned short* Kb  = (unsigned short*)(ws + oK);
    unsigned short* Vt  = (unsigned short*)(ws + oV);
    unsigned short* ATT = (unsigned short*)(ws + oATT);
    unsigned short* Wq  = (unsigned short*)(ws + oWq);
    unsigned short* Wp  = (unsigned short*)(ws + oWp);
    unsigned short* Wc  = (unsigned short*)(ws + oWc);

    kw_convert<<<256, 256, 0, stream>>>(qkv_w, proj_w, conv_w, Wq, Wp, Wc);
    k_pos<<<NN, 128, 0, stream>>>(pos_w, pos_b, P);
    k_tadd<<<dim3(49, 6, BB), 256, 0, stream>>>(x, P, XT);
    k_ln<<<BB*NN, 128, 0, stream>>>(XT, ln_g, ln_b, XN);
    k_gemm<0><<<dim3(9, 392), 256, 0, stream>>>(XN, Wq, 384, qkv_b,
        Qb, Kb, Vt, nullptr, nullptr, nullptr, nullptr, nullptr, nullptr, nullptr, nullptr);
    k_attn<<<BH, 256, 0, stream>>>(Qb, Kb, temp, rpb, ATT);
    k_pv<<<dim3(49, BH), 256, 0, stream>>>(ATT, Vt, XCA);
    k_gemm<1><<<dim3(3, 392), 256, 0, stream>>>(XCA, Wp, 384, proj_b,
        nullptr, nullptr, nullptr, XT, gxca, X2, nullptr, nullptr, nullptr, nullptr, nullptr);
    k_gemm<2><<<dim3(3, 392), 256, 0, stream>>>(X2, Wc, 3456, nullptr,
        nullptr, nullptr, nullptr, nullptr, nullptr, nullptr, bn_g, bn_b, bn_mean, bn_var, Y);
    k_final<<<dim3(56, BB, 2), 256, 0, stream>>>(x, Y, gamma, out);
}

// Round 2
// 734.717 us; speedup vs baseline: 2.1216x; 2.1216x over previous
//
#include <hip/hip_runtime.h>
#include <hip/hip_bf16.h>
#include <math.h>

#define DIM 384
#define HEADS 6
#define NN 3136
#define BB 16
#define BH (BB*HEADS)
#define HP 58
#define NP (HP*HP)   // 3364 padded image

typedef __attribute__((ext_vector_type(8))) short short8;
typedef __attribute__((ext_vector_type(4))) short short4v;
typedef __attribute__((ext_vector_type(4))) float f32x4;

__device__ __forceinline__ float bf2f(unsigned short u) {
    union { unsigned int i; float f; } v; v.i = ((unsigned int)u) << 16; return v.f;
}
__device__ __forceinline__ unsigned short f2bf(float f) {
    union { float f; unsigned int i; } v; v.f = f;
    unsigned int r = v.i + 0x7fffu + ((v.i >> 16) & 1u);
    return (unsigned short)(r >> 16);
}

// ---------------- weight conversion / rearrange ----------------
__global__ void kw_convert(const float* __restrict__ qkv_w, const float* __restrict__ proj_w,
                           const float* __restrict__ conv_w,
                           unsigned short* __restrict__ Wq, unsigned short* __restrict__ Wp,
                           unsigned short* __restrict__ Wc) {
    int tid = blockIdx.x * 256 + threadIdx.x;
    int stride = gridDim.x * 256;
    for (int i = tid; i < 3*DIM*DIM; i += stride) Wq[i] = f2bf(qkv_w[i]);
    for (int i = tid; i < DIM*DIM; i += stride) Wp[i] = f2bf(proj_w[i]);
    for (int i = tid; i < DIM*DIM*9; i += stride) {
        // dst layout: [o][tap][i]   src: (o, i, ky, kx) -> (o*384+i)*9 + tap
        int ii = i % DIM; int rest = i / DIM; int tap = rest % 9; int o = rest / 9;
        Wc[i] = f2bf(conv_w[(size_t)(o*DIM + ii)*9 + tap]);
    }
}

// ---------------- positional encoding table P[n][c] ----------------
__global__ void k_pos(const float* __restrict__ pos_w, const float* __restrict__ pos_b,
                      float* __restrict__ P) {
    int n = blockIdx.x; int h = n / 56, w = n % 56;
    __shared__ float feat[64];
    int t = threadIdx.x;
    if (t < 64) {
        int axis = t >> 5;      // 0 = y (h), 1 = x (w)
        int k = t & 31; int i = k >> 1;
        float e = (float)((axis ? w : h) + 1) / 56.000001f * 6.28318530717958647692f;
        float arg = e / powf(10000.0f, (float)i / 16.0f);
        feat[t] = (k & 1) ? cosf(arg) : sinf(arg);
    }
    __syncthreads();
    for (int c = t; c < DIM; c += blockDim.x) {
        float s = pos_b[c];
        #pragma unroll 8
        for (int k = 0; k < 64; k++) s += feat[k] * pos_w[c*64 + k];
        P[(size_t)n*DIM + c] = s;
    }
}

// ---------------- transpose + pos add: XT[b][n][c] = x[b][c][n] + P[n][c] ----------------
__global__ __launch_bounds__(256) void k_tadd(const float* __restrict__ x, const float* __restrict__ P,
                                              float* __restrict__ XT) {
    int mt = blockIdx.x, ctb = blockIdx.y, b = blockIdx.z;
    __shared__ float tile[64][65];
    int t = threadIdx.x;
    int n0 = mt*64, c0 = ctb*64;
    for (int q = t; q < 1024; q += 256) {
        int cc = q >> 4, nn4 = (q & 15) * 4;
        float4 v = *reinterpret_cast<const float4*>(x + ((size_t)(b*DIM + c0 + cc))*NN + n0 + nn4);
        tile[cc][nn4+0] = v.x; tile[cc][nn4+1] = v.y; tile[cc][nn4+2] = v.z; tile[cc][nn4+3] = v.w;
    }
    __syncthreads();
    for (int q = t; q < 1024; q += 256) {
        int nn = q >> 4, cc4 = (q & 15) * 4;
        float4 p = *reinterpret_cast<const float4*>(P + (size_t)(n0+nn)*DIM + c0 + cc4);
        float4 o;
        o.x = tile[cc4+0][nn] + p.x; o.y = tile[cc4+1][nn] + p.y;
        o.z = tile[cc4+2][nn] + p.z; o.w = tile[cc4+3][nn] + p.w;
        *reinterpret_cast<float4*>(XT + ((size_t)(b*NN + n0 + nn))*DIM + c0 + cc4) = o;
    }
}

// ---------------- layernorm: XN = LN(XT) in bf16 ----------------
__global__ __launch_bounds__(128) void k_ln(const float* __restrict__ XT, const float* __restrict__ g,
                                            const float* __restrict__ be, unsigned short* __restrict__ XN) {
    int row = blockIdx.x;
    int t = threadIdx.x;
    const float* src = XT + (size_t)row*DIM;
    float v0 = src[t], v1 = src[t+128], v2 = src[t+256];
    __shared__ float red[2], red2[2];
    float s = v0 + v1 + v2;
    for (int off = 32; off; off >>= 1) s += __shfl_down(s, off, 64);
    if ((t & 63) == 0) red[t >> 6] = s;
    __syncthreads();
    float mean = (red[0] + red[1]) * (1.0f/384.0f);
    float d0 = v0-mean, d1 = v1-mean, d2 = v2-mean;
    float sq = d0*d0 + d1*d1 + d2*d2;
    for (int off = 32; off; off >>= 1) sq += __shfl_down(sq, off, 64);
    if ((t & 63) == 0) red2[t >> 6] = sq;
    __syncthreads();
    float rs = rsqrtf((red2[0] + red2[1]) * (1.0f/384.0f) + 1e-6f);
    unsigned short* dst = XN + (size_t)row*DIM;
    dst[t]     = f2bf(d0*rs*g[t]     + be[t]);
    dst[t+128] = f2bf(d1*rs*g[t+128] + be[t+128]);
    dst[t+256] = f2bf(d2*rs*g[t+256] + be[t+256]);
}

// ---------------- unified MFMA GEMM: MODE 0 = qkv, 1 = proj, 2 = conv3x3 ----------------
// Epilogues stage C-tile in LDS and write coalesced vector runs.
template<int MODE>
__global__ __launch_bounds__(256) void k_gemm(
    const unsigned short* __restrict__ A, const unsigned short* __restrict__ Wt,
    const float* __restrict__ bias,
    unsigned short* __restrict__ Qb, unsigned short* __restrict__ Kb, unsigned short* __restrict__ Vt,
    const float* __restrict__ XTp, const float* __restrict__ gxca, unsigned short* __restrict__ X2p,
    const float* __restrict__ bn_g, const float* __restrict__ bn_b,
    const float* __restrict__ bn_mean, const float* __restrict__ bn_var,
    float* __restrict__ Yout)
{
    constexpr int K = (MODE == 2) ? 3456 : 384;
    constexpr int SMEM = (MODE == 2) ? 52736 : 35328;
    __shared__ __align__(16) char smem[SMEM];
    auto As  = (unsigned short(*)[40])smem;            // [128][40]
    auto Bs  = (unsigned short(*)[40])(smem + 10240);  // [128][40]
    auto ctA = (float(*)[69])smem;                     // [128][69]  ([o][m]) 35328B
    auto ctB = (float(*)[130])smem;                    // [64][130]  ([m][o]) 33280B
    auto X2s = (unsigned short(*)[136])(smem + 35328); // [64][136]  MODE 2 residual tile

    int ct = blockIdx.x, mt = blockIdx.y;
    int m0 = mt*128, o0 = ct*128;
    int t = threadIdx.x;
    int wave = t >> 6, lane = t & 63;
    int wr = wave >> 1, wc = wave & 1;
    int lr = lane & 15, lg = lane >> 4;

    // staging tasks: 2 rows per thread (r0, r0+64), 8 bf16 each
    int r0 = t >> 2, part = (t & 3) << 3;
    size_t baseA0, baseA1, baseB0, baseB1;
    if (MODE == 2) {
        int m = m0 + r0; int b = m/NN; int n = m - b*NN; int py = n/56, px = n - py*56;
        baseA0 = ((size_t)(b*NP + py*HP + px))*DIM + part;
        m = m0 + r0 + 64; b = m/NN; n = m - b*NN; py = n/56; px = n - py*56;
        baseA1 = ((size_t)(b*NP + py*HP + px))*DIM + part;
    } else {
        baseA0 = (size_t)(m0 + r0)*K + part;
        baseA1 = (size_t)(m0 + r0 + 64)*K + part;
    }
    baseB0 = (size_t)(o0 + r0)*K + part;
    baseB1 = (size_t)(o0 + r0 + 64)*K + part;

    f32x4 acc[4][4];
    #pragma unroll
    for (int i=0;i<4;i++) for (int j=0;j<4;j++) acc[i][j] = (f32x4){0.f,0.f,0.f,0.f};

    auto kstep = [&](size_t offA, size_t offB) {
        *(short8*)&As[r0][part]      = *(const short8*)(A  + baseA0 + offA);
        *(short8*)&As[r0+64][part]   = *(const short8*)(A  + baseA1 + offA);
        *(short8*)&Bs[r0][part]      = *(const short8*)(Wt + baseB0 + offB);
        *(short8*)&Bs[r0+64][part]   = *(const short8*)(Wt + baseB1 + offB);
        __syncthreads();
        short8 af[4], bfv[4];
        #pragma unroll
        for (int i=0;i<4;i++) af[i]  = *(short8*)&As[wr*64 + i*16 + lr][lg*8];
        #pragma unroll
        for (int j=0;j<4;j++) bfv[j] = *(short8*)&Bs[wc*64 + j*16 + lr][lg*8];
        #pragma unroll
        for (int i=0;i<4;i++)
            #pragma unroll
            for (int j=0;j<4;j++)
                acc[i][j] = __builtin_amdgcn_mfma_f32_16x16x32_bf16(af[i], bfv[j], acc[i][j], 0, 0, 0);
        __syncthreads();
    };

    if (MODE == 2) {
        for (int ty = 0; ty < 3; ty++)
            for (int tx = 0; tx < 3; tx++) {
                size_t aoff = (size_t)(ty*HP + tx)*DIM;
                size_t boff = (size_t)(ty*3 + tx)*DIM;
                for (int kk = 0; kk < 12; kk++) kstep(aoff + kk*32, boff + kk*32);
            }
    } else {
        for (int ks = 0; ks < 12; ks++) kstep((size_t)ks*32, (size_t)ks*32);
    }

    // ---- epilogue: LDS-staged coalesced writes, two m-halves ----
    int comp = (MODE == 0) ? (o0 / DIM) : 0;
    constexpr bool MODE1 = (MODE == 1);
    for (int mh = 0; mh < 2; mh++) {
        __syncthreads();
        bool useB = MODE1 || (MODE == 0 && comp == 2);
        if (wr == mh) {
            if (useB) {
                #pragma unroll
                for (int i=0;i<4;i++) for (int j=0;j<4;j++) for (int r=0;r<4;r++)
                    ctB[i*16 + lg*4 + r][wc*64 + j*16 + lr] = acc[i][j][r];
            } else {
                #pragma unroll
                for (int i=0;i<4;i++) for (int j=0;j<4;j++) for (int r=0;r<4;r++)
                    ctA[wc*64 + j*16 + lr][i*16 + lg*4 + r] = acc[i][j][r];
            }
        }
        if (MODE == 2) {
            for (int q = t; q < 1024; q += 256) {   // residual tile, 64 m x 128 o
                int row = q >> 4, seg = q & 15;
                int m = m0 + mh*64 + row; int b = m/NN; int n = m - b*NN;
                int py = n/56, px = n - py*56;
                *(short8*)&X2s[row][seg*8] =
                    *(const short8*)(A + ((size_t)(b*NP + (py+1)*HP + px + 1))*DIM + o0 + seg*8);
            }
        }
        __syncthreads();
        if (MODE == 2) {
            for (int q = t; q < 2048; q += 256) {   // 128 o-rows x 16 m-segs(4)
                int row = q >> 4, seg = q & 15;
                int o = o0 + row;
                float mean = bn_mean[o], rs = rsqrtf(bn_var[o] + 1e-5f);
                float gg = bn_g[o], bb2 = bn_b[o];
                int m4 = m0 + mh*64 + seg*4; int b = m4/NN; int n = m4 - b*NN;
                float4 ov; float* po = &ov.x;
                #pragma unroll
                for (int e=0;e<4;e++) {
                    float xi = (ctA[row][seg*4+e] - mean)*rs*gg + bb2;
                    float si = xi / (1.0f + __expf(-xi));
                    po[e] = si + bf2f(X2s[seg*4+e][row]);
                }
                *(float4*)(Yout + ((size_t)(b*DIM + o))*NN + n) = ov;
            }
        } else if (MODE == 1) {
            for (int q = t; q < 1024; q += 256) {   // 64 m-rows x 16 o-segs(8)
                int row = q >> 4, seg = q & 15;
                int m = m0 + mh*64 + row; int b = m/NN; int n = m - b*NN;
                int py = n/56, px = n - py*56;
                int og0 = o0 + seg*8;
                float xv[8];
                *(float4*)xv     = *(const float4*)(XTp + (size_t)m*DIM + og0);
                *(float4*)(xv+4) = *(const float4*)(XTp + (size_t)m*DIM + og0 + 4);
                unsigned short pk[8];
                #pragma unroll
                for (int e=0;e<8;e++) {
                    float val = ctB[row][seg*8+e] + bias[og0+e];
                    pk[e] = f2bf(xv[e] + gxca[og0+e]*val);
                }
                *(short8*)(X2p + ((size_t)(b*NP + (py+1)*HP + px + 1))*DIM + og0) = *(short8*)pk;
            }
        } else if (comp < 2) {                      // Q / K: (bh,dd,N) layout
            unsigned short* Dst = (comp == 0) ? Qb : Kb;
            for (int q = t; q < 2048; q += 256) {   // 128 o-rows x 16 m-segs(4)
                int row = q >> 4, seg = q & 15;
                int og = o0 + row; int rem = og - comp*DIM;
                int hh = rem >> 6, dd = rem & 63;
                int m4 = m0 + mh*64 + seg*4; int b = m4/NN; int n = m4 - b*NN;
                float bv = bias[og];
                unsigned short pk[4];
                #pragma unroll
                for (int e=0;e<4;e++) pk[e] = f2bf(ctA[row][seg*4+e] + bv);
                *(short4v*)(Dst + ((size_t)((b*HEADS + hh)*64 + dd))*NN + n) = *(short4v*)pk;
            }
        } else {                                    // V: (bh,N,dd) layout
            for (int q = t; q < 1024; q += 256) {   // 64 m-rows x 16 o-segs(8)
                int row = q >> 4, seg = q & 15;
                int m = m0 + mh*64 + row; int b = m/NN; int n = m - b*NN;
                int og0 = o0 + seg*8; int rem0 = og0 - 2*DIM;
                int hh = rem0 >> 6, dd0 = rem0 & 63;
                unsigned short pk[8];
                #pragma unroll
                for (int e=0;e<8;e++) pk[e] = f2bf(ctB[row][seg*8+e] + bias[og0+e]);
                *(short8*)(Vt + ((size_t)((b*HEADS + hh)*NN + n))*64 + dd0) = *(short8*)pk;
            }
        }
    }
}

// ---------------- XCA attention: norms + G=q k^T + softmax -> ATT bf16 ----------------
__global__ __launch_bounds__(256) void k_attn(const unsigned short* __restrict__ Qb,
                                              const unsigned short* __restrict__ Kb,
                                              const float* __restrict__ temperature,
                                              const float* __restrict__ rpb,
                                              unsigned short* __restrict__ ATT) {
    int bh = blockIdx.x; int h = bh % HEADS;
    int t = threadIdx.x, wave = t >> 6, lane = t & 63;
    int lr = lane & 15, lg = lane >> 4;
    __shared__ float qn[64], kn[64];
    {   // squared norms: 128 rows, 2 threads/row
        int row = t >> 1, p = t & 1;
        const unsigned short* src = (row < 64) ? Qb + ((size_t)bh*64 + row)*NN
                                               : Kb + ((size_t)bh*64 + (row-64))*NN;
        float s = 0.f;
        for (int cb = p; cb < NN/8; cb += 2) {
            short8 v = *reinterpret_cast<const short8*>(src + cb*8);
            for (int jj=0;jj<8;jj++) { float f = bf2f((unsigned short)v[jj]); s += f*f; }
        }
        s += __shfl_xor(s, 1, 64);
        if (p == 0) { if (row < 64) qn[row] = s; else kn[row-64] = s; }
    }
    __syncthreads();
    f32x4 acc[4];
    for (int j=0;j<4;j++) acc[j] = (f32x4){0.f,0.f,0.f,0.f};
    const unsigned short* qrow = Qb + ((size_t)bh*64 + wave*16 + lr)*NN;
    for (int ks = 0; ks < NN/32; ks++) {
        short8 a = *reinterpret_cast<const short8*>(qrow + ks*32 + lg*8);
        for (int j=0;j<4;j++) {
            short8 bfr = *reinterpret_cast<const short8*>(Kb + ((size_t)bh*64 + j*16 + lr)*NN + ks*32 + lg*8);
            acc[j] = __builtin_amdgcn_mfma_f32_16x16x32_bf16(a, bfr, acc[j], 0, 0, 0);
        }
    }
    float temp = temperature[h];
    float bias = rpb[HEADS + h];   // rpb_table[1][h]
    for (int r=0;r<4;r++) {
        int dq = wave*16 + lg*4 + r;
        float qnorm = fmaxf(sqrtf(qn[dq]), 1e-12f);
        float lv[4]; float mx = -1e30f;
        for (int j=0;j<4;j++) {
            float knorm = fmaxf(sqrtf(kn[j*16 + lr]), 1e-12f);
            lv[j] = acc[j][r] / (qnorm*knorm) * temp + bias;
            mx = fmaxf(mx, lv[j]);
        }
        for (int off=1; off<16; off<<=1) mx = fmaxf(mx, __shfl_xor(mx, off, 64));
        float se = 0.f;
        for (int j=0;j<4;j++) { lv[j] = __expf(lv[j]-mx); se += lv[j]; }
        for (int off=1; off<16; off<<=1) se += __shfl_xor(se, off, 64);
        float inv = 1.0f/se;
        for (int j=0;j<4;j++)
            ATT[((size_t)bh*64 + dq)*64 + j*16 + lr] = f2bf(lv[j]*inv);
    }
}

// ---------------- PV: XCA[b][n][h*64+dd] = sum_e ATT[dd][e] * V[e][n] ----------------
__global__ __launch_bounds__(256) void k_pv(const unsigned short* __restrict__ ATT,
                                            const unsigned short* __restrict__ Vt,
                                            unsigned short* __restrict__ XCA) {
    int nt = blockIdx.x, bh = blockIdx.y;
    int b = bh / HEADS, h = bh % HEADS;
    int t = threadIdx.x, wave = t >> 6, lane = t & 63;
    int lr = lane & 15, lg = lane >> 4;
    int n0 = nt*64;
    __shared__ float ctP[64][67];
    f32x4 acc[4];
    for (int i=0;i<4;i++) acc[i] = (f32x4){0.f,0.f,0.f,0.f};
    for (int ks=0; ks<2; ks++) {
        short8 bfr = *reinterpret_cast<const short8*>(Vt + ((size_t)bh*NN + n0 + wave*16 + lr)*64 + ks*32 + lg*8);
        for (int i=0;i<4;i++) {
            short8 a = *reinterpret_cast<const short8*>(ATT + ((size_t)bh*64 + i*16 + lr)*64 + ks*32 + lg*8);
            acc[i] = __builtin_amdgcn_mfma_f32_16x16x32_bf16(a, bfr, acc[i], 0, 0, 0);
        }
    }
    int nl = wave*16 + lr;
    #pragma unroll
    for (int i=0;i<4;i++)
        #pragma unroll
        for (int r=0;r<4;r++) ctP[nl][i*16 + lg*4 + r] = acc[i][r];
    __syncthreads();
    for (int q = t; q < 512; q += 256) {   // 64 n-rows x 8 dd-segs(8)
        int row = q >> 3, seg = q & 7;
        unsigned short pk[8];
        #pragma unroll
        for (int e=0;e<8;e++) pk[e] = f2bf(ctP[row][seg*8+e]);
        *(short8*)(XCA + ((size_t)(b*NN + n0 + row))*DIM + h*64 + seg*8) = *(short8*)pk;
    }
}

// ---------------- final: out = x + gamma-shuffled residual ----------------
__global__ __launch_bounds__(256) void k_final(const float* __restrict__ x, const float* __restrict__ Y,
                                               const float* __restrict__ gamma, float* __restrict__ out) {
    int i = blockIdx.x, b = blockIdx.y, kc = blockIdx.z;
    __shared__ float tile[56*193];
    int t = threadIdx.x;
    int k0 = kc*192;
    const float* ybase = Y + (size_t)b*DIM*NN + (size_t)i*21504 + k0;
    for (int q = t; q < 56*48; q += 256) {
        int j = q / 48, c4 = (q % 48) * 4;
        float4 v = *reinterpret_cast<const float4*>(ybase + (size_t)j*384 + c4);
        float* dst = &tile[j*193 + c4];
        dst[0]=v.x; dst[1]=v.y; dst[2]=v.z; dst[3]=v.w;
    }
    __syncthreads();
    for (int q = t; q < 192*56; q += 256) {
        int kl = q / 56, j = q % 56;
        int k = k0 + kl;
        size_t gi = ((size_t)(b*DIM + k))*NN + (size_t)i*56 + j;
        out[gi] = x[gi] + gamma[k] * tile[j*193 + kl];
    }
}

extern "C" void kernel_launch(void* const* d_in, const int* in_sizes, int n_in,
                              void* d_out, int out_size, void* d_ws, size_t ws_size,
                              hipStream_t stream) {
    const float* x       = (const float*)d_in[0];
    const float* pos_w   = (const float*)d_in[1];
    const float* pos_b   = (const float*)d_in[2];
    const float* ln_g    = (const float*)d_in[3];
    const float* ln_b    = (const float*)d_in[4];
    const float* gxca    = (const float*)d_in[5];
    const float* temp    = (const float*)d_in[6];
    const float* qkv_w   = (const float*)d_in[7];
    const float* qkv_b   = (const float*)d_in[8];
    const float* proj_w  = (const float*)d_in[9];
    const float* proj_b  = (const float*)d_in[10];
    const float* rpb     = (const float*)d_in[11];
    const float* conv_w  = (const float*)d_in[12];
    const float* bn_g    = (const float*)d_in[13];
    const float* bn_b    = (const float*)d_in[14];
    const float* bn_mean = (const float*)d_in[15];
    const float* bn_var  = (const float*)d_in[16];
    const float* gamma   = (const float*)d_in[17];
    float* out = (float*)d_out;
    char* ws = (char*)d_ws;

    const size_t oP   = 0;                        // P: 4,816,896 B
    const size_t oXT  = oP   + 4816896;           // XT fp32: 77,070,336 B   (reused as Y)
    const size_t oXN  = oXT  + 77070336;          // XN bf16: 38,535,168 B   (reused as XCA)
    const size_t oQ   = oXN  + 38535168;          // Qb bf16                  (reused as X2p padded, spans into Kb)
    const size_t oK   = oQ   + 38535168;          // Kb bf16
    const size_t oV   = oK   + 38535168;          // Vt bf16
    const size_t oATT = oV   + 38535168;          // ATT bf16: 786,432 B
    const size_t oWq  = oATT + 786432;            // 884,736 B
    const size_t oWp  = oWq  + 884736;            // 294,912 B
    const size_t oWc  = oWp  + 294912;            // 2,654,208 B

    float* P            = (float*)(ws + oP);
    float* XT           = (float*)(ws + oXT);
    float* Y            = (float*)(ws + oXT);     // alias (XT dead after proj epilogue)
    unsigned short* XN  = (unsigned short*)(ws + oXN);
    unsigned short* XCA = (unsigned short*)(ws + oXN);  // alias (XN dead after qkv GEMM)
    unsigned short* Qb  = (unsigned short*)(ws + oQ);
    unsigned short* X2p = (unsigned short*)(ws + oQ);   // alias (Qb+Kb dead after k_attn); 41,336,832 B padded
    unsigned short* Kb  = (unsigned short*)(ws + oK);
    unsigned short* Vt  = (unsigned short*)(ws + oV);
    unsigned short* ATT = (unsigned short*)(ws + oATT);
    unsigned short* Wq  = (unsigned short*)(ws + oWq);
    unsigned short* Wp  = (unsigned short*)(ws + oWp);
    unsigned short* Wc  = (unsigned short*)(ws + oWc);

    kw_convert<<<256, 256, 0, stream>>>(qkv_w, proj_w, conv_w, Wq, Wp, Wc);
    k_pos<<<NN, 128, 0, stream>>>(pos_w, pos_b, P);
    k_tadd<<<dim3(49, 6, BB), 256, 0, stream>>>(x, P, XT);
    k_ln<<<BB*NN, 128, 0, stream>>>(XT, ln_g, ln_b, XN);
    k_gemm<0><<<dim3(9, 392), 256, 0, stream>>>(XN, Wq, qkv_b,
        Qb, Kb, Vt, nullptr, nullptr, nullptr, nullptr, nullptr, nullptr, nullptr, nullptr);
    k_attn<<<BH, 256, 0, stream>>>(Qb, Kb, temp, rpb, ATT);
    // Q/K dead now; zero the padded X2 buffer (pad ring must be 0)
    hipMemsetAsync(X2p, 0, (size_t)BB*NP*DIM*2, stream);
    k_pv<<<dim3(49, BH), 256, 0, stream>>>(ATT, Vt, XCA);
    k_gemm<1><<<dim3(3, 392), 256, 0, stream>>>(XCA, Wp, proj_b,
        nullptr, nullptr, nullptr, XT, gxca, X2p, nullptr, nullptr, nullptr, nullptr, nullptr);
    k_gemm<2><<<dim3(3, 392), 256, 0, stream>>>(X2p, Wc, nullptr,
        nullptr, nullptr, nullptr, nullptr, nullptr, nullptr, bn_g, bn_b, bn_mean, bn_var, Y);
    k_final<<<dim3(56, BB, 2), 256, 0, stream>>>(x, Y, gamma, out);
}

// Round 3
// 633.865 us; speedup vs baseline: 2.4591x; 1.1591x over previous
//
#include <hip/hip_runtime.h>
#include <hip/hip_bf16.h>
#include <math.h>

#define DIM 384
#define HEADS 6
#define NN 3136
#define BB 16
#define BH (BB*HEADS)
#define HP 58
#define NP (HP*HP)   // 3364 padded image

typedef __attribute__((ext_vector_type(8))) short short8;
typedef __attribute__((ext_vector_type(4))) short short4v;
typedef __attribute__((ext_vector_type(4))) float f32x4;

__device__ __forceinline__ float bf2f(unsigned short u) {
    union { unsigned int i; float f; } v; v.i = ((unsigned int)u) << 16; return v.f;
}
__device__ __forceinline__ unsigned short f2bf(float f) {
    union { float f; unsigned int i; } v; v.f = f;
    unsigned int r = v.i + 0x7fffu + ((v.i >> 16) & 1u);
    return (unsigned short)(r >> 16);
}
__device__ __forceinline__ void glds16(const unsigned short* g, void* l) {
    __builtin_amdgcn_global_load_lds(
        (const __attribute__((address_space(1))) unsigned int*)g,
        (__attribute__((address_space(3))) unsigned int*)l, 16, 0, 0);
}

// ---------------- weight conversion / rearrange ----------------
__global__ void kw_convert(const float* __restrict__ qkv_w, const float* __restrict__ proj_w,
                           const float* __restrict__ conv_w,
                           unsigned short* __restrict__ Wq, unsigned short* __restrict__ Wp,
                           unsigned short* __restrict__ Wc) {
    int tid = blockIdx.x * 256 + threadIdx.x;
    int stride = gridDim.x * 256;
    for (int i = tid; i < 3*DIM*DIM; i += stride) Wq[i] = f2bf(qkv_w[i]);
    for (int i = tid; i < DIM*DIM; i += stride) Wp[i] = f2bf(proj_w[i]);
    for (int i = tid; i < DIM*DIM*9; i += stride) {
        // dst layout: [o][tap][i]   src: (o, i, ky, kx) -> (o*384+i)*9 + tap
        int ii = i % DIM; int rest = i / DIM; int tap = rest % 9; int o = rest / 9;
        Wc[i] = f2bf(conv_w[(size_t)(o*DIM + ii)*9 + tap]);
    }
}

// ---------------- positional encoding table P[n][c] ----------------
__global__ void k_pos(const float* __restrict__ pos_w, const float* __restrict__ pos_b,
                      float* __restrict__ P) {
    int n = blockIdx.x; int h = n / 56, w = n % 56;
    __shared__ float feat[64];
    int t = threadIdx.x;
    if (t < 64) {
        int axis = t >> 5;      // 0 = y (h), 1 = x (w)
        int k = t & 31; int i = k >> 1;
        float e = (float)((axis ? w : h) + 1) / 56.000001f * 6.28318530717958647692f;
        float arg = e / powf(10000.0f, (float)i / 16.0f);
        feat[t] = (k & 1) ? cosf(arg) : sinf(arg);
    }
    __syncthreads();
    for (int c = t; c < DIM; c += blockDim.x) {
        float s = pos_b[c];
        #pragma unroll 8
        for (int k = 0; k < 64; k++) s += feat[k] * pos_w[c*64 + k];
        P[(size_t)n*DIM + c] = s;
    }
}

// ---------------- transpose + pos add: XT[b][n][c] = x[b][c][n] + P[n][c] ----------------
__global__ __launch_bounds__(256) void k_tadd(const float* __restrict__ x, const float* __restrict__ P,
                                              float* __restrict__ XT) {
    int mt = blockIdx.x, ctb = blockIdx.y, b = blockIdx.z;
    __shared__ float tile[64][65];
    int t = threadIdx.x;
    int n0 = mt*64, c0 = ctb*64;
    for (int q = t; q < 1024; q += 256) {
        int cc = q >> 4, nn4 = (q & 15) * 4;
        float4 v = *reinterpret_cast<const float4*>(x + ((size_t)(b*DIM + c0 + cc))*NN + n0 + nn4);
        tile[cc][nn4+0] = v.x; tile[cc][nn4+1] = v.y; tile[cc][nn4+2] = v.z; tile[cc][nn4+3] = v.w;
    }
    __syncthreads();
    for (int q = t; q < 1024; q += 256) {
        int nn = q >> 4, cc4 = (q & 15) * 4;
        float4 p = *reinterpret_cast<const float4*>(P + (size_t)(n0+nn)*DIM + c0 + cc4);
        float4 o;
        o.x = tile[cc4+0][nn] + p.x; o.y = tile[cc4+1][nn] + p.y;
        o.z = tile[cc4+2][nn] + p.z; o.w = tile[cc4+3][nn] + p.w;
        *reinterpret_cast<float4*>(XT + ((size_t)(b*NN + n0 + nn))*DIM + c0 + cc4) = o;
    }
}

// ---------------- layernorm: XN = LN(XT) in bf16 ----------------
__global__ __launch_bounds__(128) void k_ln(const float* __restrict__ XT, const float* __restrict__ g,
                                            const float* __restrict__ be, unsigned short* __restrict__ XN) {
    int row = blockIdx.x;
    int t = threadIdx.x;
    const float* src = XT + (size_t)row*DIM;
    float v0 = src[t], v1 = src[t+128], v2 = src[t+256];
    __shared__ float red[2], red2[2];
    float s = v0 + v1 + v2;
    for (int off = 32; off; off >>= 1) s += __shfl_down(s, off, 64);
    if ((t & 63) == 0) red[t >> 6] = s;
    __syncthreads();
    float mean = (red[0] + red[1]) * (1.0f/384.0f);
    float d0 = v0-mean, d1 = v1-mean, d2 = v2-mean;
    float sq = d0*d0 + d1*d1 + d2*d2;
    for (int off = 32; off; off >>= 1) sq += __shfl_down(sq, off, 64);
    if ((t & 63) == 0) red2[t >> 6] = sq;
    __syncthreads();
    float rs = rsqrtf((red2[0] + red2[1]) * (1.0f/384.0f) + 1e-6f);
    unsigned short* dst = XN + (size_t)row*DIM;
    dst[t]     = f2bf(d0*rs*g[t]     + be[t]);
    dst[t+128] = f2bf(d1*rs*g[t+128] + be[t+128]);
    dst[t+256] = f2bf(d2*rs*g[t+256] + be[t+256]);
}

// ---------------- MFMA GEMM (K=384): MODE 0 = qkv, 1 = proj ----------------
// global_load_lds staging, XCD-swizzled 1D grid, LDS-staged coalesced epilogues.
template<int MODE>
__global__ __launch_bounds__(256) void k_gemm(
    const unsigned short* __restrict__ A, const unsigned short* __restrict__ Wt,
    const float* __restrict__ bias,
    unsigned short* __restrict__ Qb, unsigned short* __restrict__ Kb, unsigned short* __restrict__ Vt,
    const float* __restrict__ XTp, const float* __restrict__ gxca, unsigned short* __restrict__ X2p)
{
    __shared__ __align__(16) char smem[35328];
    auto As  = (unsigned short(*)[32])smem;            // [128][32] 8192
    auto Bs  = (unsigned short(*)[32])(smem + 8192);   // [128][32] 8192
    auto ctA = (float(*)[69])smem;                     // [128][69] 35328  ([o][m])
    auto ctB = (float(*)[130])smem;                    // [64][130] 33280  ([m][o])

    constexpr int NCT = (MODE == 0) ? 9 : 3;
    constexpr int CPX = (MODE == 0) ? 441 : 147;       // 392*NCT/8
    int bid = blockIdx.x;
    int orig = (bid & 7)*CPX + (bid >> 3);
    int ct = orig % NCT, mt = orig / NCT;
    int m0 = mt*128, o0 = ct*128;
    int t = threadIdx.x;
    int wave = t >> 6, lane = t & 63;
    int wr = wave >> 1, wc = wave & 1;
    int lr = lane & 15, lg = lane >> 4;

    int r0 = t >> 2, sg8 = (t & 3) << 3;
    const unsigned short* a0 = A  + (size_t)(m0 + r0)*384 + sg8;
    const unsigned short* a1 = A  + (size_t)(m0 + 64 + r0)*384 + sg8;
    const unsigned short* b0 = Wt + (size_t)(o0 + r0)*384 + sg8;
    const unsigned short* b1 = Wt + (size_t)(o0 + 64 + r0)*384 + sg8;

    f32x4 acc[4][4];
    #pragma unroll
    for (int i=0;i<4;i++) for (int j=0;j<4;j++) acc[i][j] = (f32x4){0.f,0.f,0.f,0.f};

    for (int kk = 0; kk < 12; kk++) {
        int c = kk*32;
        glds16(a0 + c, smem + 0     + wave*1024);
        glds16(a1 + c, smem + 4096  + wave*1024);
        glds16(b0 + c, smem + 8192  + wave*1024);
        glds16(b1 + c, smem + 12288 + wave*1024);
        __syncthreads();
        short8 af[4], bfv[4];
        #pragma unroll
        for (int i=0;i<4;i++) af[i]  = *(short8*)&As[wr*64 + i*16 + lr][lg*8];
        #pragma unroll
        for (int j=0;j<4;j++) bfv[j] = *(short8*)&Bs[wc*64 + j*16 + lr][lg*8];
        #pragma unroll
        for (int i=0;i<4;i++)
            #pragma unroll
            for (int j=0;j<4;j++)
                acc[i][j] = __builtin_amdgcn_mfma_f32_16x16x32_bf16(af[i], bfv[j], acc[i][j], 0, 0, 0);
        __syncthreads();
    }

    // ---- epilogue ----
    int comp = (MODE == 0) ? (o0 / DIM) : 0;
    for (int mh = 0; mh < 2; mh++) {
        __syncthreads();
        bool useB = (MODE == 1) || (MODE == 0 && comp == 2);
        if (wr == mh) {
            if (useB) {
                #pragma unroll
                for (int i=0;i<4;i++) for (int j=0;j<4;j++) for (int r=0;r<4;r++)
                    ctB[i*16 + lg*4 + r][wc*64 + j*16 + lr] = acc[i][j][r];
            } else {
                #pragma unroll
                for (int i=0;i<4;i++) for (int j=0;j<4;j++) for (int r=0;r<4;r++)
                    ctA[wc*64 + j*16 + lr][i*16 + lg*4 + r] = acc[i][j][r];
            }
        }
        __syncthreads();
        if (MODE == 1) {
            for (int q = t; q < 1024; q += 256) {   // 64 m-rows x 16 o-segs(8)
                int row = q >> 4, seg = q & 15;
                int m = m0 + mh*64 + row; int b = m/NN; int n = m - b*NN;
                int py = n/56, px = n - py*56;
                int og0 = o0 + seg*8;
                float xv[8];
                *(float4*)xv     = *(const float4*)(XTp + (size_t)m*DIM + og0);
                *(float4*)(xv+4) = *(const float4*)(XTp + (size_t)m*DIM + og0 + 4);
                unsigned short pk[8];
                #pragma unroll
                for (int e=0;e<8;e++) {
                    float val = ctB[row][seg*8+e] + bias[og0+e];
                    pk[e] = f2bf(xv[e] + gxca[og0+e]*val);
                }
                *(short8*)(X2p + ((size_t)(b*NP + (py+1)*HP + px + 1))*DIM + og0) = *(short8*)pk;
            }
        } else if (comp < 2) {                      // Q / K: (bh,dd,N) layout
            unsigned short* Dst = (comp == 0) ? Qb : Kb;
            for (int q = t; q < 2048; q += 256) {   // 128 o-rows x 16 m-segs(4)
                int row = q >> 4, seg = q & 15;
                int og = o0 + row; int rem = og - comp*DIM;
                int hh = rem >> 6, dd = rem & 63;
                int m4 = m0 + mh*64 + seg*4; int b = m4/NN; int n = m4 - b*NN;
                float bv = bias[og];
                unsigned short pk[4];
                #pragma unroll
                for (int e=0;e<4;e++) pk[e] = f2bf(ctA[row][seg*4+e] + bv);
                *(short4v*)(Dst + ((size_t)((b*HEADS + hh)*64 + dd))*NN + n) = *(short4v*)pk;
            }
        } else {                                    // V: (bh,N,dd) layout
            for (int q = t; q < 1024; q += 256) {   // 64 m-rows x 16 o-segs(8)
                int row = q >> 4, seg = q & 15;
                int m = m0 + mh*64 + row; int b = m/NN; int n = m - b*NN;
                int og0 = o0 + seg*8; int rem0 = og0 - 2*DIM;
                int hh = rem0 >> 6, dd0 = rem0 & 63;
                unsigned short pk[8];
                #pragma unroll
                for (int e=0;e<8;e++) pk[e] = f2bf(ctB[row][seg*8+e] + bias[og0+e]);
                *(short8*)(Vt + ((size_t)((b*HEADS + hh)*NN + n))*64 + dd0) = *(short8*)pk;
            }
        }
    }
}

// ---------------- conv3x3 + BN + SiLU + residual, halo-LDS single-read of A ----------------
// Grid: 1200 blocks (16 b x 25 tiles x 3 ct), XCD-swizzled. A = X2p padded bf16.
__global__ __launch_bounds__(256) void k_conv(
    const unsigned short* __restrict__ A, const unsigned short* __restrict__ Wt,
    const float* __restrict__ bn_g, const float* __restrict__ bn_b,
    const float* __restrict__ bn_mean, const float* __restrict__ bn_var,
    float* __restrict__ Yout)
{
    __shared__ __align__(16) char smem[32768];
    auto Ah  = (unsigned short(*)[32])smem;            // [256][32] 16384 (position halo)
    auto Bs  = (unsigned short(*)[32])(smem + 16384);  // [2][128][32] 16384
    auto ctA = (float(*)[69])smem;                     // [64][69] 17664
    auto X2s = (unsigned short(*)[72])(smem + 17664);  // [64][72] 9216

    int bid = blockIdx.x;                 // 1200 = 8*150
    int orig = (bid & 7)*150 + (bid >> 3);
    int ct = orig % 3; int rest = orig / 3;
    int tile = rest % 25; int b = rest / 25;
    int n0 = tile*128, o0 = ct*128;
    int t = threadIdx.x;
    int wave = t >> 6, lane = t & 63;
    int wr = wave >> 1, wc = wave & 1;
    int lr = lane & 15, lg = lane >> 4;
    int qb = n0 + 2*(n0/56);
    const size_t bbase = (size_t)b*NP*DIM;

    // A-halo staging sources: 1024 tasks (256 rows x 4 segs of 16B), row = pos qb+row
    const unsigned short* asrc[4];
    #pragma unroll
    for (int j=0;j<4;j++) {
        int task = j*256 + t;
        int row = task >> 2, sg = task & 3;
        int q = qb + row; if (q > NP-1) q = NP-1;
        asrc[j] = A + bbase + (size_t)q*DIM + sg*8;
    }
    // B staging sources (128 rows x 4 segs = 512 tasks, 2 rounds)
    int br = t >> 2, bsg = (t & 3) << 3;
    const unsigned short* bsrc0 = Wt + (size_t)(o0 + br)*3456 + bsg;
    const unsigned short* bsrc1 = Wt + (size_t)(o0 + 64 + br)*3456 + bsg;

    // per-lane MFMA A row offsets (position-relative)
    int qrel[4];
    #pragma unroll
    for (int i=0;i<4;i++) {
        int loc = wr*64 + i*16 + lr;
        int n = n0 + loc; if (n >= NN) n = NN-1;
        qrel[i] = n + 2*(n/56) - qb;
    }

    f32x4 acc[4][4];
    #pragma unroll
    for (int i=0;i<4;i++) for (int j=0;j<4;j++) acc[i][j] = (f32x4){0.f,0.f,0.f,0.f};

    for (int kk = 0; kk < 12; kk++) {
        int c = kk*32;
        #pragma unroll
        for (int j=0;j<4;j++)
            glds16(asrc[j] + c, smem + j*4096 + wave*1024);
        // stage B tap 0 into buf 0
        glds16(bsrc0 + c, smem + 16384 + wave*1024);
        glds16(bsrc1 + c, smem + 16384 + 4096 + wave*1024);
        __syncthreads();
        #pragma unroll
        for (int tap = 0; tap < 9; tap++) {
            int buf = tap & 1;
            if (tap < 8) {
                int cn = (tap+1)*384 + c;
                char* base = smem + 16384 + (buf^1)*8192;
                glds16(bsrc0 + cn, base + wave*1024);
                glds16(bsrc1 + cn, base + 4096 + wave*1024);
            }
            int toff = (tap/3)*58 + (tap%3);
            short8 af[4], bfv[4];
            #pragma unroll
            for (int i=0;i<4;i++) af[i]  = *(short8*)&Ah[qrel[i] + toff][lg*8];
            #pragma unroll
            for (int j=0;j<4;j++) bfv[j] = *(short8*)&Bs[buf*128 + wc*64 + j*16 + lr][lg*8];
            #pragma unroll
            for (int i=0;i<4;i++)
                #pragma unroll
                for (int j=0;j<4;j++)
                    acc[i][j] = __builtin_amdgcn_mfma_f32_16x16x32_bf16(af[i], bfv[j], acc[i][j], 0, 0, 0);
            __syncthreads();
        }
    }

    // ---- epilogue: 4 quadrant passes (mh x oh), coalesced float4 writes ----
    for (int mh = 0; mh < 2; mh++) {
        for (int oh = 0; oh < 2; oh++) {
            __syncthreads();
            if (wr == mh && wc == oh) {
                #pragma unroll
                for (int i=0;i<4;i++) for (int j=0;j<4;j++) for (int r=0;r<4;r++)
                    ctA[j*16 + lr][i*16 + lg*4 + r] = acc[i][j][r];
            }
            for (int q = t; q < 512; q += 256) {    // residual: 64 m-rows x 8 o-segs(8)
                int row = q >> 3, sg = q & 7;
                int n = n0 + mh*64 + row; int nc = (n < NN) ? n : NN-1;
                int qq = nc + 2*(nc/56) + 59;       // center tap (+1,+1)
                *(short8*)&X2s[row][sg*8] =
                    *(const short8*)(A + bbase + (size_t)qq*DIM + o0 + oh*64 + sg*8);
            }
            __syncthreads();
            for (int q = t; q < 1024; q += 256) {   // 64 o-rows x 16 m-segs(4)
                int orow = q >> 4, sg = q & 15;
                int o = o0 + oh*64 + orow;
                int n = n0 + mh*64 + sg*4;
                if (n < NN) {
                    float mean = bn_mean[o], rs = rsqrtf(bn_var[o] + 1e-5f);
                    float gg = bn_g[o], bb2 = bn_b[o];
                    float4 ov; float* po = &ov.x;
                    #pragma unroll
                    for (int e=0;e<4;e++) {
                        float xi = (ctA[orow][sg*4+e] - mean)*rs*gg + bb2;
                        float si = xi / (1.0f + __expf(-xi));
                        po[e] = si + bf2f(X2s[sg*4+e][orow]);
                    }
                    *(float4*)(Yout + ((size_t)(b*DIM + o))*NN + n) = ov;
                }
            }
        }
    }
}

// ---------------- XCA attention: norms + G=q k^T + softmax -> ATT bf16 ----------------
__global__ __launch_bounds__(256) void k_attn(const unsigned short* __restrict__ Qb,
                                              const unsigned short* __restrict__ Kb,
                                              const float* __restrict__ temperature,
                                              const float* __restrict__ rpb,
                                              unsigned short* __restrict__ ATT) {
    int bh = blockIdx.x; int h = bh % HEADS;
    int t = threadIdx.x, wave = t >> 6, lane = t & 63;
    int lr = lane & 15, lg = lane >> 4;
    __shared__ float qn[64], kn[64];
    {   // squared norms: 128 rows, 2 threads/row
        int row = t >> 1, p = t & 1;
        const unsigned short* src = (row < 64) ? Qb + ((size_t)bh*64 + row)*NN
                                               : Kb + ((size_t)bh*64 + (row-64))*NN;
        float s = 0.f;
        for (int cb = p; cb < NN/8; cb += 2) {
            short8 v = *reinterpret_cast<const short8*>(src + cb*8);
            for (int jj=0;jj<8;jj++) { float f = bf2f((unsigned short)v[jj]); s += f*f; }
        }
        s += __shfl_xor(s, 1, 64);
        if (p == 0) { if (row < 64) qn[row] = s; else kn[row-64] = s; }
    }
    __syncthreads();
    f32x4 acc[4];
    for (int j=0;j<4;j++) acc[j] = (f32x4){0.f,0.f,0.f,0.f};
    const unsigned short* qrow = Qb + ((size_t)bh*64 + wave*16 + lr)*NN;
    for (int ks = 0; ks < NN/32; ks++) {
        short8 a = *reinterpret_cast<const short8*>(qrow + ks*32 + lg*8);
        for (int j=0;j<4;j++) {
            short8 bfr = *reinterpret_cast<const short8*>(Kb + ((size_t)bh*64 + j*16 + lr)*NN + ks*32 + lg*8);
            acc[j] = __builtin_amdgcn_mfma_f32_16x16x32_bf16(a, bfr, acc[j], 0, 0, 0);
        }
    }
    float temp = temperature[h];
    float bias = rpb[HEADS + h];   // rpb_table[1][h]
    for (int r=0;r<4;r++) {
        int dq = wave*16 + lg*4 + r;
        float qnorm = fmaxf(sqrtf(qn[dq]), 1e-12f);
        float lv[4]; float mx = -1e30f;
        for (int j=0;j<4;j++) {
            float knorm = fmaxf(sqrtf(kn[j*16 + lr]), 1e-12f);
            lv[j] = acc[j][r] / (qnorm*knorm) * temp + bias;
            mx = fmaxf(mx, lv[j]);
        }
        for (int off=1; off<16; off<<=1) mx = fmaxf(mx, __shfl_xor(mx, off, 64));
        float se = 0.f;
        for (int j=0;j<4;j++) { lv[j] = __expf(lv[j]-mx); se += lv[j]; }
        for (int off=1; off<16; off<<=1) se += __shfl_xor(se, off, 64);
        float inv = 1.0f/se;
        for (int j=0;j<4;j++)
            ATT[((size_t)bh*64 + dq)*64 + j*16 + lr] = f2bf(lv[j]*inv);
    }
}

// ---------------- PV: XCA[b][n][h*64+dd] = sum_e ATT[dd][e] * V[e][n] ----------------
__global__ __launch_bounds__(256) void k_pv(const unsigned short* __restrict__ ATT,
                                            const unsigned short* __restrict__ Vt,
                                            unsigned short* __restrict__ XCA) {
    int nt = blockIdx.x, bh = blockIdx.y;
    int b = bh / HEADS, h = bh % HEADS;
    int t = threadIdx.x, wave = t >> 6, lane = t & 63;
    int lr = lane & 15, lg = lane >> 4;
    int n0 = nt*64;
    __shared__ float ctP[64][67];
    f32x4 acc[4];
    for (int i=0;i<4;i++) acc[i] = (f32x4){0.f,0.f,0.f,0.f};
    for (int ks=0; ks<2; ks++) {
        short8 bfr = *reinterpret_cast<const short8*>(Vt + ((size_t)bh*NN + n0 + wave*16 + lr)*64 + ks*32 + lg*8);
        for (int i=0;i<4;i++) {
            short8 a = *reinterpret_cast<const short8*>(ATT + ((size_t)bh*64 + i*16 + lr)*64 + ks*32 + lg*8);
            acc[i] = __builtin_amdgcn_mfma_f32_16x16x32_bf16(a, bfr, acc[i], 0, 0, 0);
        }
    }
    int nl = wave*16 + lr;
    #pragma unroll
    for (int i=0;i<4;i++)
        #pragma unroll
        for (int r=0;r<4;r++) ctP[nl][i*16 + lg*4 + r] = acc[i][r];
    __syncthreads();
    for (int q = t; q < 512; q += 256) {   // 64 n-rows x 8 dd-segs(8)
        int row = q >> 3, seg = q & 7;
        unsigned short pk[8];
        #pragma unroll
        for (int e=0;e<8;e++) pk[e] = f2bf(ctP[row][seg*8+e]);
        *(short8*)(XCA + ((size_t)(b*NN + n0 + row))*DIM + h*64 + seg*8) = *(short8*)pk;
    }
}

// ---------------- final: out = x + gamma-shuffled residual ----------------
__global__ __launch_bounds__(256) void k_final(const float* __restrict__ x, const float* __restrict__ Y,
                                               const float* __restrict__ gamma, float* __restrict__ out) {
    int i = blockIdx.x, b = blockIdx.y, kc = blockIdx.z;
    __shared__ float tile[56*193];
    int t = threadIdx.x;
    int k0 = kc*192;
    const float* ybase = Y + (size_t)b*DIM*NN + (size_t)i*21504 + k0;
    for (int q = t; q < 56*48; q += 256) {
        int j = q / 48, c4 = (q % 48) * 4;
        float4 v = *reinterpret_cast<const float4*>(ybase + (size_t)j*384 + c4);
        float* dst = &tile[j*193 + c4];
        dst[0]=v.x; dst[1]=v.y; dst[2]=v.z; dst[3]=v.w;
    }
    __syncthreads();
    for (int q = t; q < 192*56; q += 256) {
        int kl = q / 56, j = q % 56;
        int k = k0 + kl;
        size_t gi = ((size_t)(b*DIM + k))*NN + (size_t)i*56 + j;
        out[gi] = x[gi] + gamma[k] * tile[j*193 + kl];
    }
}

extern "C" void kernel_launch(void* const* d_in, const int* in_sizes, int n_in,
                              void* d_out, int out_size, void* d_ws, size_t ws_size,
                              hipStream_t stream) {
    const float* x       = (const float*)d_in[0];
    const float* pos_w   = (const float*)d_in[1];
    const float* pos_b   = (const float*)d_in[2];
    const float* ln_g    = (const float*)d_in[3];
    const float* ln_b    = (const float*)d_in[4];
    const float* gxca    = (const float*)d_in[5];
    const float* temp    = (const float*)d_in[6];
    const float* qkv_w   = (const float*)d_in[7];
    const float* qkv_b   = (const float*)d_in[8];
    const float* proj_w  = (const float*)d_in[9];
    const float* proj_b  = (const float*)d_in[10];
    const float* rpb     = (const float*)d_in[11];
    const float* conv_w  = (const float*)d_in[12];
    const float* bn_g    = (const float*)d_in[13];
    const float* bn_b    = (const float*)d_in[14];
    const float* bn_mean = (const float*)d_in[15];
    const float* bn_var  = (const float*)d_in[16];
    const float* gamma   = (const float*)d_in[17];
    float* out = (float*)d_out;
    char* ws = (char*)d_ws;

    const size_t oP   = 0;                        // P: 4,816,896 B
    const size_t oXT  = oP   + 4816896;           // XT fp32: 77,070,336 B   (reused as Y)
    const size_t oXN  = oXT  + 77070336;          // XN bf16: 38,535,168 B   (reused as XCA)
    const size_t oQ   = oXN  + 38535168;          // Qb bf16                  (reused as X2p padded, spans into Kb)
    const size_t oK   = oQ   + 38535168;          // Kb bf16
    const size_t oV   = oK   + 38535168;          // Vt bf16
    const size_t oATT = oV   + 38535168;          // ATT bf16: 786,432 B
    const size_t oWq  = oATT + 786432;            // 884,736 B
    const size_t oWp  = oWq  + 884736;            // 294,912 B
    const size_t oWc  = oWp  + 294912;            // 2,654,208 B

    float* P            = (float*)(ws + oP);
    float* XT           = (float*)(ws + oXT);
    float* Y            = (float*)(ws + oXT);     // alias (XT dead after proj epilogue)
    unsigned short* XN  = (unsigned short*)(ws + oXN);
    unsigned short* XCA = (unsigned short*)(ws + oXN);  // alias (XN dead after qkv GEMM)
    unsigned short* Qb  = (unsigned short*)(ws + oQ);
    unsigned short* X2p = (unsigned short*)(ws + oQ);   // alias (Qb+Kb dead after k_attn); 41,336,832 B padded
    unsigned short* Kb  = (unsigned short*)(ws + oK);
    unsigned short* Vt  = (unsigned short*)(ws + oV);
    unsigned short* ATT = (unsigned short*)(ws + oATT);
    unsigned short* Wq  = (unsigned short*)(ws + oWq);
    unsigned short* Wp  = (unsigned short*)(ws + oWp);
    unsigned short* Wc  = (unsigned short*)(ws + oWc);

    kw_convert<<<256, 256, 0, stream>>>(qkv_w, proj_w, conv_w, Wq, Wp, Wc);
    k_pos<<<NN, 128, 0, stream>>>(pos_w, pos_b, P);
    k_tadd<<<dim3(49, 6, BB), 256, 0, stream>>>(x, P, XT);
    k_ln<<<BB*NN, 128, 0, stream>>>(XT, ln_g, ln_b, XN);
    k_gemm<0><<<3528, 256, 0, stream>>>(XN, Wq, qkv_b,
        Qb, Kb, Vt, nullptr, nullptr, nullptr);
    k_attn<<<BH, 256, 0, stream>>>(Qb, Kb, temp, rpb, ATT);
    // Q/K dead now; zero the padded X2 buffer (pad ring must be 0)
    hipMemsetAsync(X2p, 0, (size_t)BB*NP*DIM*2, stream);
    k_pv<<<dim3(49, BH), 256, 0, stream>>>(ATT, Vt, XCA);
    k_gemm<1><<<1176, 256, 0, stream>>>(XCA, Wp, proj_b,
        nullptr, nullptr, nullptr, XT, gxca, X2p);
    k_conv<<<1200, 256, 0, stream>>>(X2p, Wc, bn_g, bn_b, bn_mean, bn_var, Y);
    k_final<<<dim3(56, BB, 2), 256, 0, stream>>>(x, Y, gamma, out);
}